// Round 1
// baseline (51.375 us; speedup 1.0000x reference)
//
#include <hip/hip_runtime.h>

// Problem constants (from reference setup_inputs): B=4096, K=64, N=256.
// d_in[0] = x (float32, B*K*N), d_in[1] = k, d_in[2] = n (device scalars, unused —
// reading them would require a sync that breaks graph capture; values are fixed
// by the problem definition).
// d_out = [pred (B*K floats)] ++ [y (K*N*K floats)], both float32.

constexpr int K = 64;
constexpr int N = 256;

// One wave (64 lanes) per output element (b,k). Lane l loads the float4 at
// x4[out*64 + l] -> the wave's 64 lanes cover exactly the 256-float segment
// contiguously (1024 B per wave-instruction, fully coalesced).
__global__ __launch_bounds__(256) void seg_sum_kernel(const float4* __restrict__ x4,
                                                      float* __restrict__ pred) {
    const int lane = threadIdx.x & 63;
    const int wave = threadIdx.x >> 6;
    const long long out_idx = (long long)blockIdx.x * 4 + wave;

    float4 v = x4[out_idx * (N / 4) + lane];
    float s = (v.x + v.y) + (v.z + v.w);

    // 64-lane wave reduction (CDNA wave = 64).
    #pragma unroll
    for (int off = 32; off >= 1; off >>= 1)
        s += __shfl_down(s, off, 64);

    if (lane == 0) pred[out_idx] = s;
}

// y[r][c] = (r / N == c) ? 1 : 0, written as float4 (K=64 divisible by 4).
// Row has K/4 = 16 float4s; N = 256 rows per hot column.
__global__ __launch_bounds__(256) void eye_rep_kernel(float4* __restrict__ y4) {
    const int i = blockIdx.x * blockDim.x + threadIdx.x;   // float4 index
    const int r = i >> 4;           // / (K/4)
    const int cb = (i & 15) << 2;   // column base
    const int hot = r >> 8;         // r / N
    float4 v;
    v.x = (cb + 0 == hot) ? 1.0f : 0.0f;
    v.y = (cb + 1 == hot) ? 1.0f : 0.0f;
    v.z = (cb + 2 == hot) ? 1.0f : 0.0f;
    v.w = (cb + 3 == hot) ? 1.0f : 0.0f;
    y4[i] = v;
}

extern "C" void kernel_launch(void* const* d_in, const int* in_sizes, int n_in,
                              void* d_out, int out_size, void* d_ws, size_t ws_size,
                              hipStream_t stream) {
    const float* x = (const float*)d_in[0];
    float* out = (float*)d_out;

    const int B = in_sizes[0] / (K * N);        // 4096
    float* pred = out;                           // B*K floats
    float* y = out + (size_t)B * K;              // K*N*K floats

    // B*K outputs, 4 per block (4 waves of 64) -> B*K/4 blocks.
    seg_sum_kernel<<<(B * K) / 4, 256, 0, stream>>>(
        reinterpret_cast<const float4*>(x), pred);

    // K*N*K/4 float4 stores.
    eye_rep_kernel<<<(K * N * K / 4) / 256, 256, 0, stream>>>(
        reinterpret_cast<float4*>(y));
}